// Round 10
// baseline (805.734 us; speedup 1.0000x reference)
//
#include <hip/hip_runtime.h>
#include <math.h>

#define NN 50000
#define NE 400000
#define RSQRT32 0.17677669529663687f

typedef __attribute__((ext_vector_type(8))) short bf16x8;
typedef __attribute__((ext_vector_type(4))) float f32x4;
#define MFMA_B16(a, b, c) __builtin_amdgcn_mfma_f32_16x16x32_bf16(a, b, c, 0, 0, 0)

// ---------------- workspace layout (bytes) ----------------
#define O_FLAG  0ULL
#define O_BSUM  256ULL                         // 196 ints (scan block sums)
#define O_SRCI  1280ULL                        // E*4
#define O_DSTI  (O_SRCI + 1600000ULL)          // E*4 -> s1 alias after scatter
#define O_DEG   (O_DSTI + 1600000ULL)          // N*4
#define O_CUR   (O_DEG + 200192ULL)            // N*4 -> s2 alias
#define O_START (O_CUR + 200192ULL)            // (N+1)*4
#define O_SRCS  (O_START + 200704ULL)          // E*4
#define O_ORIG  (O_SRCS + 1600000ULL)          // E*4
#define O_RELT  (O_ORIG + 1600000ULL)          // E*4
#define O_Q1    (O_RELT + 1600000ULL)          // N*256*2 bf16; later Q2/K2/V2/S2m fp32
#define O_K1    (O_Q1 + 25600000ULL)           // bf16; later G2 fp32
#define O_V1    (O_K1 + 25600000ULL)           // bf16; later h bf16
#define O_S1M   (O_V1 + 25600000ULL)           // bf16; later A2 fp32
#define O_G1    (O_S1M + 25600000ULL)          // N*1024*2 bf16; A1 aliases exactly; later numv2
#define O_WB1   (O_G1 + 102400000ULL)          // [4][256][128] bf16
#define O_WG1   (O_WB1 + 262144ULL)            // [8][128][32] bf16
#define O_WF1   (O_WG1 + 65536ULL)             // [8][32][128] bf16
#define O_WB2   (O_WF1 + 65536ULL)             // [128][256] bf16
#define O_NUMV1 (O_WB2 + 65536ULL)             // N*256*4 fp32 (dedicated: Q1/K1 live during agg)
#define WS_TOTAL (O_NUMV1 + 51200000ULL)
// aliases
#define O_S1    O_DSTI                         // N*8*4
#define O_A1    O_G1                           // N*1024*2 bf16 (exact overlay of G1)
#define O_H     O_V1                           // N*256*2 bf16
#define O_Q2    O_Q1                           // N*32*4 fp32
#define O_K2    (O_Q1 + 6400000ULL)
#define O_V2    (O_Q1 + 12800000ULL)
#define O_S2M   (O_Q1 + 19200000ULL)
#define O_G2    O_K1                           // N*128*4 fp32
#define O_A2    O_S1M                          // N*128*4 fp32
#define O_NUMV2 O_G1                           // N*32*4 fp32
#define O_S2    O_CUR                          // N*4

__device__ __forceinline__ unsigned short f2bf(float f) {
    unsigned int u = __float_as_uint(f);
    unsigned int r = (u + 0x7fffu + ((u >> 16) & 1u)) >> 16;
    return (unsigned short)r;
}
__device__ __forceinline__ float bf2f(unsigned short u) {
    return __uint_as_float(((unsigned int)u) << 16);
}
__device__ __forceinline__ float4 ld_bf16x4(const unsigned short* p) {
    const ushort4 u = *(const ushort4*)p;
    float4 r;
    r.x = bf2f(u.x); r.y = bf2f(u.y); r.z = bf2f(u.z); r.w = bf2f(u.w);
    return r;
}
__device__ __forceinline__ ushort4 st_bf16x4(float a, float b, float c, float d) {
    ushort4 u; u.x = f2bf(a); u.y = f2bf(b); u.z = f2bf(c); u.w = f2bf(d);
    return u;
}

// ---------------- index dtype detect ----------------
__global__ void k_detect(const unsigned int* ei, int* flag) {
    if (threadIdx.x == 0) {
        int is64 = 1;
        for (int i = 0; i < 64; ++i)
            if (ei[2 * i + 1] != 0u) { is64 = 0; break; }
        *flag = is64;
    }
}

// ---------------- convert + degree histogram (fused) ----------------
__global__ void k_convhist(const void* ei, const int* flag,
                           int* __restrict__ srcI, int* __restrict__ dstI,
                           int* __restrict__ deg) {
    int i = blockIdx.x * 256 + threadIdx.x;
    if (i >= NE) return;
    int s, d;
    if (*flag) {
        const long long* p = (const long long*)ei;
        s = (int)p[i]; d = (int)p[NE + i];
    } else {
        const int* p = (const int*)ei;
        s = p[i]; d = p[NE + i];
    }
    srcI[i] = s;
    dstI[i] = d;
    atomicAdd(&deg[d], 1);
}

// ---------------- parallel 3-phase exclusive scan over deg ----------------
__global__ void k_scanA(const int* __restrict__ deg, int* __restrict__ locs,
                        int* __restrict__ bsum) {
    __shared__ int sm[256];
    const int t = threadIdx.x;
    const int gidx = blockIdx.x * 256 + t;
    int v = (gidx < NN) ? deg[gidx] : 0;
    sm[t] = v;
    __syncthreads();
    for (int off = 1; off < 256; off <<= 1) {
        int u = (t >= off) ? sm[t - off] : 0;
        __syncthreads();
        sm[t] += u;
        __syncthreads();
    }
    if (gidx < NN) locs[gidx] = sm[t];          // inclusive local scan
    if (t == 255) bsum[blockIdx.x] = sm[255];
}

__global__ void k_scanB(int* __restrict__ bsum) {
    __shared__ int sm[256];
    const int t = threadIdx.x;
    int v = (t < 196) ? bsum[t] : 0;
    sm[t] = v;
    __syncthreads();
    for (int off = 1; off < 256; off <<= 1) {
        int u = (t >= off) ? sm[t - off] : 0;
        __syncthreads();
        sm[t] += u;
        __syncthreads();
    }
    if (t < 196) bsum[t] = sm[t] - v;           // exclusive block offsets
}

__global__ void k_scanC(const int* __restrict__ deg, const int* __restrict__ bsum,
                        int* __restrict__ startA, int* __restrict__ cursor) {
    const int t = threadIdx.x;
    const int gidx = blockIdx.x * 256 + t;
    if (gidx < NN) {
        const int ex = startA[gidx] - deg[gidx] + bsum[blockIdx.x];
        startA[gidx] = ex;
        cursor[gidx] = ex;
    }
    if (gidx == 0) startA[NN] = NE;
}

__global__ void k_scatter(const int* __restrict__ srcI, const int* __restrict__ dstI,
                          const float* __restrict__ lu, const float* __restrict__ tE,
                          int* __restrict__ cursor,
                          int* __restrict__ srcS, int* __restrict__ orig,
                          float* __restrict__ relT) {
    int i = blockIdx.x * 256 + threadIdx.x;
    if (i >= NE) return;
    const int d = dstI[i];
    const int s = srcI[i];
    const int pos = atomicAdd(&cursor[d], 1);
    srcS[pos] = s;
    orig[pos] = i;
    relT[pos] = lu[s] - tE[i];
}

// ---------------- weight prep: pack bf16 B^T forms ----------------
__global__ void k_prepw(
    const float* __restrict__ Wq1, const float* __restrict__ Wk1,
    const float* __restrict__ Wv1, const float* __restrict__ Ws1,
    const float* __restrict__ We1,
    const float* __restrict__ Wq2, const float* __restrict__ Wk2,
    const float* __restrict__ Wv2, const float* __restrict__ Ws2,
    unsigned short* __restrict__ WB1, unsigned short* __restrict__ WG1,
    unsigned short* __restrict__ WF1, unsigned short* __restrict__ WB2)
{
    const int i = blockIdx.x * 256 + threadIdx.x;
    if (i < 131072) {                       // WB1[part][n 256][k 128]
        const int part = i >> 15;
        const int rem = i & 32767;
        const int n = rem >> 7, k = rem & 127;
        const float* W = part == 0 ? Wq1 : part == 1 ? Wk1 : part == 2 ? Wv1 : Ws1;
        WB1[i] = f2bf(W[(size_t)k * 256 + n]);
    } else if (i < 163840) {                // WG1[h][ko 128][c 32]
        const int j = i - 131072;
        const int h = j >> 12, ko = (j >> 5) & 127, c = j & 31;
        WG1[j] = f2bf(We1[(size_t)ko * 256 + h * 32 + c]);
    } else if (i < 196608) {                // WF1[h][c 32][ko 128]
        const int j = i - 163840;
        const int h = j >> 12, c = (j >> 7) & 31, ko = j & 127;
        WF1[j] = f2bf(We1[(size_t)ko * 256 + h * 32 + c]);
    } else if (i < 229376) {                // WB2[col 128][k 256]
        const int j = i - 196608;
        const int col = j >> 8, k = j & 255;
        const int part = col >> 5, pc = col & 31;
        const float* W = part == 0 ? Wq2 : part == 1 ? Wk2 : part == 2 ? Wv2 : Ws2;
        WB2[j] = f2bf(W[(size_t)k * 32 + pc]);
    }
}

// ---------------- MFMA node GEMM layer 1 ----------------
__global__ __launch_bounds__(256) void k_gemm1m(
    const float* __restrict__ x, const unsigned short* __restrict__ WB1,
    const float* __restrict__ c0, const float* __restrict__ c1,
    const float* __restrict__ c2, const float* __restrict__ c3,
    unsigned short* __restrict__ Q1b, unsigned short* __restrict__ K1b,
    unsigned short* __restrict__ V1b, unsigned short* __restrict__ S1mb)
{
    __shared__ unsigned short As[64 * 136];
    __shared__ unsigned short Bs[64 * 136];
    const int t = threadIdx.x;
    const int row0 = blockIdx.x * 64;
    const int by = blockIdx.y;
    const int part = by >> 2;
    const int pcol0 = (by & 3) * 64;
    const float* bp = part == 0 ? c0 : part == 1 ? c1 : part == 2 ? c2 : c3;
    unsigned short* Ob = part == 0 ? Q1b : part == 1 ? K1b : part == 2 ? V1b : S1mb;

    {
        const int r = t >> 2, cc = (t & 3) * 32;
        const int gr = row0 + r;
        unsigned short* dst = As + r * 136 + cc;
        if (gr < NN) {
            const float4* xp = (const float4*)(x + (size_t)gr * 128 + cc);
            #pragma unroll
            for (int i = 0; i < 8; ++i) {
                const float4 v = xp[i];
                *(ushort4*)(dst + 4 * i) = st_bf16x4(v.x, v.y, v.z, v.w);
            }
        } else {
            const ushort4 z = {0, 0, 0, 0};
            #pragma unroll
            for (int i = 0; i < 8; ++i) *(ushort4*)(dst + 4 * i) = z;
        }
    }
    {
        const int n = t >> 2, kk = (t & 3) * 32;
        const unsigned short* src = WB1 + ((size_t)part * 256 + pcol0 + n) * 128 + kk;
        unsigned short* dst = Bs + n * 136 + kk;
        #pragma unroll
        for (int i = 0; i < 4; ++i)
            *(bf16x8*)(dst + 8 * i) = *(const bf16x8*)(src + 8 * i);
    }
    __syncthreads();

    const int w = t >> 6, lane = t & 63, m = lane & 15, quad = lane >> 4;
    f32x4 acc[4];
    #pragma unroll
    for (int i = 0; i < 4; ++i) acc[i] = (f32x4){0.f, 0.f, 0.f, 0.f};
    #pragma unroll
    for (int kc = 0; kc < 4; ++kc) {
        const bf16x8 af = *(const bf16x8*)(As + (16 * w + m) * 136 + kc * 32 + quad * 8);
        #pragma unroll
        for (int ct = 0; ct < 4; ++ct) {
            const bf16x8 bf = *(const bf16x8*)(Bs + (16 * ct + m) * 136 + kc * 32 + quad * 8);
            acc[ct] = MFMA_B16(af, bf, acc[ct]);
        }
    }
    #pragma unroll
    for (int ct = 0; ct < 4; ++ct) {
        const int colp = pcol0 + ct * 16 + m;
        const float b = bp[colp];
        #pragma unroll
        for (int r = 0; r < 4; ++r) {
            const int gr = row0 + 16 * w + quad * 4 + r;
            if (gr < NN) Ob[(size_t)gr * 256 + colp] = f2bf(acc[ct][r] + b);
        }
    }
}

// ---------------- MFMA G1 ----------------
__global__ __launch_bounds__(256) void k_g1m(
    const unsigned short* __restrict__ Q1b, const unsigned short* __restrict__ WG1,
    unsigned short* __restrict__ G1b)
{
    __shared__ unsigned short As[64 * 40];
    __shared__ unsigned short Bs[128 * 40];
    const int t = threadIdx.x;
    const int n0 = blockIdx.x * 64;
    const int h = blockIdx.y;
    {
        const int n = t >> 2, c = (t & 3) * 8;
        const int gn = n0 + n;
        bf16x8 v = {};
        if (gn < NN) v = *(const bf16x8*)(Q1b + (size_t)gn * 256 + h * 32 + c);
        *(bf16x8*)(As + n * 40 + c) = v;
    }
    {
        const int ko = t >> 1, c = (t & 1) * 16;
        const unsigned short* src = WG1 + (size_t)h * 4096 + ko * 32 + c;
        *(bf16x8*)(Bs + ko * 40 + c) = *(const bf16x8*)(src);
        *(bf16x8*)(Bs + ko * 40 + c + 8) = *(const bf16x8*)(src + 8);
    }
    __syncthreads();

    const int w = t >> 6, lane = t & 63, m = lane & 15, quad = lane >> 4;
    f32x4 acc[8];
    #pragma unroll
    for (int i = 0; i < 8; ++i) acc[i] = (f32x4){0.f, 0.f, 0.f, 0.f};
    const bf16x8 af = *(const bf16x8*)(As + (16 * w + m) * 40 + quad * 8);
    #pragma unroll
    for (int ct = 0; ct < 8; ++ct) {
        const bf16x8 bf = *(const bf16x8*)(Bs + (16 * ct + m) * 40 + quad * 8);
        acc[ct] = MFMA_B16(af, bf, acc[ct]);
    }
    #pragma unroll
    for (int ct = 0; ct < 8; ++ct) {
        const int k = ct * 16 + m;
        #pragma unroll
        for (int r = 0; r < 4; ++r) {
            const int gn = n0 + 16 * w + quad * 4 + r;
            if (gn < NN) G1b[(size_t)gn * 1024 + h * 128 + k] = f2bf(acc[ct][r]);
        }
    }
}

// ---------------- G2 (fp32) ----------------
__global__ __launch_bounds__(256) void k_g2(
    const float* __restrict__ Q2, const float* __restrict__ We2,
    float* __restrict__ G2)
{
    __shared__ float Qs[64][36];
    __shared__ float Ws[128][36];
    const int t = threadIdx.x;
    const int n0 = blockIdx.x * 64;
    {
        const int n = t >> 2, c8 = (t & 3) * 8;
        float4 v0 = make_float4(0.f,0.f,0.f,0.f), v1 = v0;
        if (n0 + n < NN) {
            v0 = *(const float4*)(Q2 + (size_t)(n0 + n) * 32 + c8);
            v1 = *(const float4*)(Q2 + (size_t)(n0 + n) * 32 + c8 + 4);
        }
        *(float4*)(&Qs[n][c8]) = v0;
        *(float4*)(&Qs[n][c8 + 4]) = v1;
    }
    {
        const int k = t >> 1, c16 = (t & 1) * 16;
        #pragma unroll
        for (int i = 0; i < 4; ++i)
            *(float4*)(&Ws[k][c16 + 4 * i]) =
                *(const float4*)(We2 + (size_t)k * 32 + c16 + 4 * i);
    }
    __syncthreads();
    const int tx = t & 15, ty = t >> 4;
    const int k8 = tx * 8, n4 = ty * 4;
    float acc[4][8] = {};
    #pragma unroll 8
    for (int c = 0; c < 32; ++c) {
        float a[4], b[8];
        #pragma unroll
        for (int i = 0; i < 4; ++i) a[i] = Qs[n4 + i][c];
        #pragma unroll
        for (int j = 0; j < 8; ++j) b[j] = Ws[k8 + j][c];
        #pragma unroll
        for (int i = 0; i < 4; ++i)
            #pragma unroll
            for (int j = 0; j < 8; ++j)
                acc[i][j] += a[i] * b[j];
    }
    #pragma unroll
    for (int i = 0; i < 4; ++i) {
        const int gn = n0 + n4 + i;
        if (gn < NN) {
            float* gp = G2 + (size_t)gn * 128 + k8;
            *(float4*)(gp)     = make_float4(acc[i][0], acc[i][1], acc[i][2], acc[i][3]);
            *(float4*)(gp + 4) = make_float4(acc[i][4], acc[i][5], acc[i][6], acc[i][7]);
        }
    }
}

// ---- k_agg1 pipeline macros: named stage locals, NEVER address-taken, no
// runtime-indexed arrays (rule #20). Depth 2. Round-10: PERSISTENT grid-stride
// waves (grid 4096 x 64thr; each wave loops over dst-pairs). Evidence: round-9
// 25000 tiny workgroups at ~2us each = ~128 wg/us sustained dispatch -- likely
// at the CP's small-wg dispatch throughput (occupancy stuck ~31% despite >=16
// wave/CU capacity, no pipe saturated). Persistent waves remove dispatch from
// the critical path; tw/tb loads hoisted loop-invariant.
#define AGG1_ISSUE(S, JJ)                                                     \
    {                                                                         \
        const int s_ = __shfl(sv, base32 + (JJ));                             \
        rS##S = __shfl(rv, base32 + (JJ));                                    \
        const int o_ = __shfl(ov, base32 + (JJ));                             \
        kS##S = *(const bf16x8*)(kbase + (size_t)s_ * 256);                   \
        vS##S = *(const bf16x8*)(vbase + (size_t)s_ * 256);                   \
        if (l >= 16)                                                          \
            mS##S = *(const float4*)(msg + (size_t)o_ * 64 + (l - 16) * 4);   \
    }

#define AGG1_BODY(KC, VC, MC, RC)                                             \
    {                                                                         \
        float a0_, a1_, a2_, a3_;                                             \
        if (l < 16) {                                                         \
            a0_ = __cosf((RC) * twl.x + tbl.x);                               \
            a1_ = __cosf((RC) * twl.y + tbl.y);                               \
            a2_ = __cosf((RC) * twl.z + tbl.z);                               \
            a3_ = __cosf((RC) * twl.w + tbl.w);                               \
        } else {                                                              \
            a0_ = (MC).x; a1_ = (MC).y; a2_ = (MC).z; a3_ = (MC).w;           \
        }                                                                     \
        float qk_;                                                            \
        {                                                                     \
            float kf[8];                                                      \
            _Pragma("unroll")                                                 \
            for (int i = 0; i < 8; ++i) kf[i] = bf2f((unsigned short)(KC)[i]); \
            qk_ = q8[0]*kf[0] + q8[1]*kf[1] + q8[2]*kf[2] + q8[3]*kf[3]       \
                + q8[4]*kf[4] + q8[5]*kf[5] + q8[6]*kf[6] + q8[7]*kf[7];      \
        }                                                                     \
        float part[8];                                                        \
        _Pragma("unroll")                                                     \
        for (int h = 0; h < 8; ++h)                                           \
            part[h] = a0_*gv[h][0] + a1_*gv[h][1] + a2_*gv[h][2]              \
                    + a3_*gv[h][3] + (h == hl ? qk_ : 0.f);                   \
        float t4[4];                                                          \
        {                                                                     \
            const bool b_ = (l & 1) != 0;                                     \
            _Pragma("unroll")                                                 \
            for (int i = 0; i < 4; ++i) {                                     \
                const float give = b_ ? part[i] : part[4 + i];                \
                const float keep = b_ ? part[4 + i] : part[i];                \
                t4[i] = keep + __shfl_xor(give, 1);                           \
            }                                                                 \
        }                                                                     \
        float t2[2];                                                          \
        {                                                                     \
            const bool b_ = (l & 2) != 0;                                     \
            _Pragma("unroll")                                                 \
            for (int i = 0; i < 2; ++i) {                                     \
                const float give = b_ ? t4[i] : t4[2 + i];                    \
                const float keep = b_ ? t4[2 + i] : t4[i];                    \
                t2[i] = keep + __shfl_xor(give, 2);                           \
            }                                                                 \
        }                                                                     \
        float t1;                                                             \
        {                                                                     \
            const bool b_ = (l & 4) != 0;                                     \
            const float give = b_ ? t2[0] : t2[1];                            \
            const float keep = b_ ? t2[1] : t2[0];                            \
            t1 = keep + __shfl_xor(give, 4);                                  \
        }                                                                     \
        t1 += __shfl_xor(t1, 8);                                              \
        t1 += __shfl_xor(t1, 16);                                             \
        const float pe = __expf(fminf(t1 * RSQRT32, 80.f));                   \
        /* lane brev3(h) holds head h; pv for this lane's head via 1 shfl */  \
        float p_all[8];                                                       \
        p_all[0] = __shfl(pe, base32 + 0);                                    \
        p_all[1] = __shfl(pe, base32 + 4);                                    \
        p_all[2] = __shfl(pe, base32 + 2);                                    \
        p_all[3] = __shfl(pe, base32 + 6);                                    \
        p_all[4] = __shfl(pe, base32 + 1);                                    \
        p_all[5] = __shfl(pe, base32 + 5);                                    \
        p_all[6] = __shfl(pe, base32 + 3);                                    \
        p_all[7] = __shfl(pe, base32 + 7);                                    \
        const float pv = __shfl(pe, pvl);                                     \
        _Pragma("unroll")                                                     \
        for (int h = 0; h < 8; ++h) {                                         \
            a1acc[h][0] += p_all[h]*a0_; a1acc[h][1] += p_all[h]*a1_;         \
            a1acc[h][2] += p_all[h]*a2_; a1acc[h][3] += p_all[h]*a3_;         \
        }                                                                     \
        {                                                                     \
            float vf[8];                                                      \
            _Pragma("unroll")                                                 \
            for (int i = 0; i < 8; ++i) vf[i] = bf2f((unsigned short)(VC)[i]); \
            nv[0] += pv*vf[0]; nv[1] += pv*vf[1]; nv[2] += pv*vf[2]; nv[3] += pv*vf[3]; \
            nv[4] += pv*vf[4]; nv[5] += pv*vf[5]; nv[6] += pv*vf[6]; nv[7] += pv*vf[7]; \
            sacc += pv;                                                       \
        }                                                                     \
    }

// ---------------- FUSED layer-1 attention + aggregation (dst-centric) ----------
// Persistent: 1-wave blocks, grid-stride over dst-pairs. Lane-parallel
// srcS/relT/orig chunk loads + 2-deep register pipeline + halving butterfly.
__global__ __launch_bounds__(64) __attribute__((amdgpu_waves_per_eu(3)))
void k_agg1(
    const int* __restrict__ startA, const int* __restrict__ srcS,
    const int* __restrict__ orig, const float* __restrict__ relT,
    const float* __restrict__ msg, const float* __restrict__ tw,
    const float* __restrict__ tb,
    const unsigned short* __restrict__ Q1b, const unsigned short* __restrict__ K1b,
    const unsigned short* __restrict__ V1b, const unsigned short* G1b,
    unsigned short* A1b, float* __restrict__ numv1, float* __restrict__ s1)
{
    const int t = threadIdx.x;
    const int g = t >> 5, l = t & 31;
    const int base32 = (t & 63) & 32;
    const int hl = l >> 2;   // head owning this lane's 8-channel q/k/v slice
    // lane holding this head's reduced logit: brev3(hl) within the half-wave
    const int pvl = base32 + (((hl & 1) << 2) | (hl & 2) | (hl >> 2));

    float4 twl = make_float4(0.f,0.f,0.f,0.f), tbl = twl;
    if (l < 16) {
        twl = *(const float4*)(tw + l * 4);
        tbl = *(const float4*)(tb + l * 4);
    }

    const unsigned short* kbase = K1b + l * 8;
    const unsigned short* vbase = V1b + l * 8;

    for (int dp = blockIdx.x; dp < NN / 2; dp += gridDim.x) {
        const int d = dp * 2 + g;
        const int eb = startA[d], ee = startA[d + 1];

        float q8[8];
        {
            const unsigned short* qp = Q1b + (size_t)d * 256 + l * 8;
            const float4 q0 = ld_bf16x4(qp), q1 = ld_bf16x4(qp + 4);
            q8[0]=q0.x; q8[1]=q0.y; q8[2]=q0.z; q8[3]=q0.w;
            q8[4]=q1.x; q8[5]=q1.y; q8[6]=q1.z; q8[7]=q1.w;
        }
        float gv[8][4];
        #pragma unroll
        for (int h = 0; h < 8; ++h) {
            const float4 gg = ld_bf16x4(G1b + (size_t)d * 1024 + h * 128 + l * 4);
            gv[h][0]=gg.x; gv[h][1]=gg.y; gv[h][2]=gg.z; gv[h][3]=gg.w;
        }

        float a1acc[8][4] = {};
        float nv[8] = {};
        float sacc = 0.f;

        for (int c = eb; c < ee; c += 32) {
            const int cnt = (ee - c < 32) ? (ee - c) : 32;
            const bool lvld = (c + l) < ee;
            const int   sv = lvld ? srcS[c + l] : 0;    // lane-parallel, coalesced
            const float rv = lvld ? relT[c + l] : 0.f;
            const int   ov = lvld ? orig[c + l] : 0;

            bf16x8 kS0 = {}, vS0 = {}, kS1 = {}, vS1 = {};
            float4 mS0 = make_float4(0.f,0.f,0.f,0.f), mS1 = mS0;
            float  rS0 = 0.f, rS1 = 0.f;

            AGG1_ISSUE(0, 0);
            if (cnt > 1) AGG1_ISSUE(1, 1);
            for (int j = 0; j < cnt; j += 2) {
                {
                    const bf16x8 kc_ = kS0, vc_ = vS0;
                    const float4 mc_ = mS0;
                    const float  rc_ = rS0;
                    if (j + 2 < cnt) AGG1_ISSUE(0, j + 2);
                    AGG1_BODY(kc_, vc_, mc_, rc_)
                }
                if (j + 1 < cnt) {
                    const bf16x8 kc_ = kS1, vc_ = vS1;
                    const float4 mc_ = mS1;
                    const float  rc_ = rS1;
                    if (j + 3 < cnt) AGG1_ISSUE(1, j + 3);
                    AGG1_BODY(kc_, vc_, mc_, rc_)
                }
            }
        }

        #pragma unroll
        for (int h = 0; h < 8; ++h)
            *(ushort4*)(A1b + (size_t)d * 1024 + h * 128 + l * 4) =
                st_bf16x4(a1acc[h][0], a1acc[h][1], a1acc[h][2], a1acc[h][3]);
        float* np = numv1 + (size_t)d * 256 + l * 8;
        *(float4*)(np)     = make_float4(nv[0], nv[1], nv[2], nv[3]);
        *(float4*)(np + 4) = make_float4(nv[4], nv[5], nv[6], nv[7]);
        if ((l & 3) == 0) s1[(size_t)d * 8 + hl] = sacc;
    }
}

// ---------------- MFMA fold layer 1 ----------------
__global__ __launch_bounds__(256) void k_foldC1m(
    const unsigned short* __restrict__ A1b, const unsigned short* __restrict__ WF1,
    const float* __restrict__ numv1, const float* __restrict__ s1,
    const unsigned short* __restrict__ S1mb, unsigned short* __restrict__ hb)
{
    __shared__ unsigned short As[64 * 136];
    __shared__ unsigned short Bs[32 * 136];
    const int t = threadIdx.x;
    const int n0 = blockIdx.x * 64;
    const int h = blockIdx.y;
    {
        const int n = t >> 2, kk = (t & 3) * 32;
        const int gn = n0 + n;
        unsigned short* dst = As + n * 136 + kk;
        if (gn < NN) {
            const unsigned short* src = A1b + (size_t)gn * 1024 + h * 128 + kk;
            #pragma unroll
            for (int i = 0; i < 4; ++i)
                *(bf16x8*)(dst + 8 * i) = *(const bf16x8*)(src + 8 * i);
        } else {
            const bf16x8 z = {};
            #pragma unroll
            for (int i = 0; i < 4; ++i) *(bf16x8*)(dst + 8 * i) = z;
        }
    }
    {
        const int c = t >> 3, kk = (t & 7) * 16;
        const unsigned short* src = WF1 + (size_t)h * 4096 + c * 128 + kk;
        *(bf16x8*)(Bs + c * 136 + kk) = *(const bf16x8*)(src);
        *(bf16x8*)(Bs + c * 136 + kk + 8) = *(const bf16x8*)(src + 8);
    }
    __syncthreads();

    const int w = t >> 6, lane = t & 63, m = lane & 15, quad = lane >> 4;
    f32x4 acc[2];
    acc[0] = (f32x4){0.f, 0.f, 0.f, 0.f};
    acc[1] = (f32x4){0.f, 0.f, 0.f, 0.f};
    #pragma unroll
    for (int kc = 0; kc < 4; ++kc) {
        const bf16x8 af = *(const bf16x8*)(As + (16 * w + m) * 136 + kc * 32 + quad * 8);
        #pragma unroll
        for (int ct = 0; ct < 2; ++ct) {
            const bf16x8 bf = *(const bf16x8*)(Bs + (16 * ct + m) * 136 + kc * 32 + quad * 8);
            acc[ct] = MFMA_B16(af, bf, acc[ct]);
        }
    }
    #pragma unroll
    for (int ct = 0; ct < 2; ++ct) {
        const int c = ct * 16 + m;
        #pragma unroll
        for (int r = 0; r < 4; ++r) {
            const int gn = n0 + 16 * w + quad * 4 + r;
            if (gn < NN) {
                const float s = s1[(size_t)gn * 8 + h] + 1e-16f;
                const float nvv = numv1[(size_t)gn * 256 + h * 32 + c];
                const float sk = bf2f(S1mb[(size_t)gn * 256 + h * 32 + c]);
                float v = (acc[ct][r] + nvv) / s + sk;
                v = v > 0.f ? v : 0.f;
                hb[(size_t)gn * 256 + h * 32 + c] = f2bf(v);
            }
        }
    }
}

// ---------------- MFMA node GEMM layer 2 ----------------
__global__ __launch_bounds__(256) void k_gemm2m(
    const unsigned short* __restrict__ hb, const unsigned short* __restrict__ WB2,
    const float* __restrict__ c0, const float* __restrict__ c1,
    const float* __restrict__ c2, const float* __restrict__ c3,
    float* __restrict__ O0, float* __restrict__ O1,
    float* __restrict__ O2, float* __restrict__ O3)
{
    __shared__ unsigned short As[64 * 136];
    __shared__ unsigned short Bs[64 * 136];
    const int t = threadIdx.x;
    const int row0 = blockIdx.x * 64;
    const int coly = blockIdx.y;
    const int w = t >> 6, lane = t & 63, m = lane & 15, quad = lane >> 4;

    f32x4 acc[4];
    #pragma unroll
    for (int i = 0; i < 4; ++i) acc[i] = (f32x4){0.f, 0.f, 0.f, 0.f};

    for (int kb = 0; kb < 2; ++kb) {
        if (kb) __syncthreads();
        {
            const int r = t >> 2, kk = (t & 3) * 32;
            const int gr = row0 + r;
            unsigned short* dst = As + r * 136 + kk;
            if (gr < NN) {
                const unsigned short* src = hb + (size_t)gr * 256 + kb * 128 + kk;
                #pragma unroll
                for (int i = 0; i < 4; ++i)
                    *(bf16x8*)(dst + 8 * i) = *(const bf16x8*)(src + 8 * i);
            } else {
                const bf16x8 z = {};
                #pragma unroll
                for (int i = 0; i < 4; ++i) *(bf16x8*)(dst + 8 * i) = z;
            }
        }
        {
            const int n = t >> 2, kk = (t & 3) * 32;
            const unsigned short* src = WB2 + (size_t)(coly * 64 + n) * 256 + kb * 128 + kk;
            unsigned short* dst = Bs + n * 136 + kk;
            #pragma unroll
            for (int i = 0; i < 4; ++i)
                *(bf16x8*)(dst + 8 * i) = *(const bf16x8*)(src + 8 * i);
        }
        __syncthreads();
        #pragma unroll
        for (int kc = 0; kc < 4; ++kc) {
            const bf16x8 af = *(const bf16x8*)(As + (16 * w + m) * 136 + kc * 32 + quad * 8);
            #pragma unroll
            for (int ct = 0; ct < 4; ++ct) {
                const bf16x8 bf = *(const bf16x8*)(Bs + (16 * ct + m) * 136 + kc * 32 + quad * 8);
                acc[ct] = MFMA_B16(af, bf, acc[ct]);
            }
        }
    }
    #pragma unroll
    for (int ct = 0; ct < 4; ++ct) {
        const int col = coly * 64 + ct * 16 + m;
        const int part = col >> 5, pc = col & 31;
        const float* bb = part == 0 ? c0 : part == 1 ? c1 : part == 2 ? c2 : c3;
        float* Op = part == 0 ? O0 : part == 1 ? O1 : part == 2 ? O2 : O3;
        const float b = bb[pc];
        #pragma unroll
        for (int r = 0; r < 4; ++r) {
            const int gr = row0 + 16 * w + quad * 4 + r;
            if (gr < NN) Op[(size_t)gr * 32 + pc] = acc[ct][r] + b;
        }
    }
}

// ---- k_aggB2 pipeline macros (same named-stage discipline, depth 2) ----
#define AGG2_ISSUE(S, JJ)                                                     \
    {                                                                         \
        const int s_ = __shfl(sv, base32 + (JJ));                             \
        rS##S = __shfl(rv, base32 + (JJ));                                    \
        const int o_ = __shfl(ov, base32 + (JJ));                             \
        kS##S = K2[(size_t)s_ * 32 + l];                                      \
        vS##S = V2[(size_t)s_ * 32 + l];                                      \
        if (l >= 16)                                                          \
            mS##S = *(const float4*)(msg + (size_t)o_ * 64 + (l - 16) * 4);   \
    }

#define AGG2_BODY(KC, VC, MC, RC)                                             \
    {                                                                         \
        float a0_, a1_, a2_, a3_;                                             \
        if (l < 16) {                                                         \
            a0_ = __cosf((RC) * twl.x + tbl.x);                               \
            a1_ = __cosf((RC) * twl.y + tbl.y);                               \
            a2_ = __cosf((RC) * twl.z + tbl.z);                               \
            a3_ = __cosf((RC) * twl.w + tbl.w);                               \
        } else {                                                              \
            a0_ = (MC).x; a1_ = (MC).y; a2_ = (MC).z; a3_ = (MC).w;           \
        }                                                                     \
        float part = q2l * (KC);                                              \
        part += a0_ * g2l.x + a1_ * g2l.y + a2_ * g2l.z + a3_ * g2l.w;        \
        part += __shfl_xor(part, 1);                                          \
        part += __shfl_xor(part, 2);                                          \
        part += __shfl_xor(part, 4);                                          \
        part += __shfl_xor(part, 8);                                          \
        part += __shfl_xor(part, 16);                                         \
        const float p = __expf(fminf(part * RSQRT32, 80.f));                  \
        acc2[0] += p * a0_; acc2[1] += p * a1_;                               \
        acc2[2] += p * a2_; acc2[3] += p * a3_;                               \
        nvacc += p * (VC);                                                    \
        sacc += p;                                                            \
    }

// ---------------- layer 2 fused p + aggregate (persistent grid-stride) ------
__global__ __launch_bounds__(64) __attribute__((amdgpu_waves_per_eu(4)))
void k_aggB2(
    const int* __restrict__ startA, const int* __restrict__ srcS,
    const int* __restrict__ orig, const float* __restrict__ relT,
    const float* __restrict__ msg, const float* __restrict__ tw,
    const float* __restrict__ tb,
    const float* __restrict__ Q2, const float* __restrict__ K2,
    const float* __restrict__ V2, const float* __restrict__ G2,
    float* __restrict__ A2, float* __restrict__ numv2, float* __restrict__ s2)
{
    const int t = threadIdx.x;
    const int g = t >> 5, l = t & 31;
    const int base32 = (t & 63) & 32;

    float4 twl = make_float4(0.f,0.f,0.f,0.f), tbl = twl;
    if (l < 16) {
        twl = *(const float4*)(tw + l * 4);
        tbl = *(const float4*)(tb + l * 4);
    }

    for (int dp = blockIdx.x; dp < NN / 2; dp += gridDim.x) {
        const int d = dp * 2 + g;
        const int eb = startA[d], ee = startA[d + 1];

        const float q2l = Q2[(size_t)d * 32 + l];
        const float4 g2l = *(const float4*)(G2 + (size_t)d * 128 + l * 4);
        float acc2[4] = {};
        float nvacc = 0.f, sacc = 0.f;

        for (int c = eb; c < ee; c += 32) {
            const int cnt = (ee - c < 32) ? (ee - c) : 32;
            const bool lvld = (c + l) < ee;
            const int   sv = lvld ? srcS[c + l] : 0;
            const float rv = lvld ? relT[c + l] : 0.f;
            const int   ov = lvld ? orig[c + l] : 0;

            float kS0 = 0.f, vS0 = 0.f, kS1 = 0.f, vS1 = 0.f;
            float rS0 = 0.f, rS1 = 0.f;
            float4 mS0 = make_float4(0.f,0.f,0.f,0.f), mS1 = mS0;

            AGG2_ISSUE(0, 0);
            if (cnt > 1) AGG2_ISSUE(1, 1);
            for (int j = 0; j < cnt; j += 2) {
                {
                    const float kc_ = kS0, vc_ = vS0;
                    const float4 mc_ = mS0;
                    const float  rc_ = rS0;
                    if (j + 2 < cnt) AGG2_ISSUE(0, j + 2);
                    AGG2_BODY(kc_, vc_, mc_, rc_)
                }
                if (j + 1 < cnt) {
                    const float kc_ = kS1, vc_ = vS1;
                    const float4 mc_ = mS1;
                    const float  rc_ = rS1;
                    if (j + 3 < cnt) AGG2_ISSUE(1, j + 3);
                    AGG2_BODY(kc_, vc_, mc_, rc_)
                }
            }
        }

        *(float4*)(A2 + (size_t)d * 128 + l * 4) =
            make_float4(acc2[0], acc2[1], acc2[2], acc2[3]);
        numv2[(size_t)d * 32 + l] = nvacc;
        if (l == 0) s2[d] = sacc;
    }
}

// ---------------- fold layer 2 ----------------
__global__ __launch_bounds__(256) void k_foldC2(
    const float* __restrict__ A2, const float* __restrict__ We2,
    const float* __restrict__ numv2, const float* __restrict__ s2,
    const float* __restrict__ S2m, float* __restrict__ out)
{
    __shared__ float Ws[128][36];
    const int t = threadIdx.x;
    {
        const int k = t >> 1, c16 = (t & 1) * 16;
        #pragma unroll
        for (int i = 0; i < 4; ++i)
            *(float4*)(&Ws[k][c16 + 4 * i]) =
                *(const float4*)(We2 + (size_t)k * 32 + c16 + 4 * i);
    }
    __syncthreads();
    const int n = blockIdx.x * 8 + (t >> 5);
    const int c = t & 31;
    const float* ap = A2 + (size_t)n * 128;
    float acc = 0.f;
    #pragma unroll 8
    for (int k = 0; k < 128; k += 4) {
        const float4 a4 = *(const float4*)(ap + k);
        acc += a4.x * Ws[k][c] + a4.y * Ws[k + 1][c] +
               a4.z * Ws[k + 2][c] + a4.w * Ws[k + 3][c];
    }
    const float s = s2[n] + 1e-16f;
    float v = (numv2[(size_t)n * 32 + c] + acc) / s + S2m[(size_t)n * 32 + c];
    out[(size_t)n * 32 + c] = v > 0.f ? v : 0.f;
}

extern "C" void kernel_launch(void* const* d_in, const int* in_sizes, int n_in,
                              void* d_out, int out_size, void* d_ws, size_t ws_size,
                              hipStream_t stream) {
    const float* x   = (const float*)d_in[0];
    const float* lu  = (const float*)d_in[1];
    const void*  ei  = d_in[2];
    const float* tE  = (const float*)d_in[3];
    const float* msg = (const float*)d_in[4];
    const float* tw  = (const float*)d_in[5];
    const float* tb  = (const float*)d_in[6];
    const float* Wq1 = (const float*)d_in[7];  const float* bq1 = (const float*)d_in[8];
    const float* Wk1 = (const float*)d_in[9];  const float* bk1 = (const float*)d_in[10];
    const float* Wv1 = (const float*)d_in[11]; const float* bv1 = (const float*)d_in[12];
    const float* We1 = (const float*)d_in[13];
    const float* Ws1 = (const float*)d_in[14]; const float* bs1 = (const float*)d_in[15];
    const float* Wq2 = (const float*)d_in[16]; const float* bq2 = (const float*)d_in[17];
    const float* Wk2 = (const float*)d_in[18]; const float* bk2 = (const float*)d_in[19];
    const float* Wv2 = (const float*)d_in[20]; const float* bv2 = (const float*)d_in[21];
    const float* We2 = (const float*)d_in[22];
    const float* Ws2 = (const float*)d_in[23]; const float* bs2 = (const float*)d_in[24];
    float* out = (float*)d_out;
    char* ws = (char*)d_ws;

    if (ws_size < WS_TOTAL) return;

    int* flag   = (int*)(ws + O_FLAG);
    int* bsum   = (int*)(ws + O_BSUM);
    int* srcI   = (int*)(ws + O_SRCI);
    int* dstI   = (int*)(ws + O_DSTI);
    int* deg    = (int*)(ws + O_DEG);
    int* cursor = (int*)(ws + O_CUR);
    int* startA = (int*)(ws + O_START);
    int* srcS   = (int*)(ws + O_SRCS);
    int* orig   = (int*)(ws + O_ORIG);
    float* relT = (float*)(ws + O_RELT);
    unsigned short* Q1b  = (unsigned short*)(ws + O_Q1);
    unsigned short* K1b  = (unsigned short*)(ws + O_K1);
    unsigned short* V1b  = (unsigned short*)(ws + O_V1);
    unsigned short* S1mb = (unsigned short*)(ws + O_S1M);
    unsigned short* G1b  = (unsigned short*)(ws + O_G1);
    unsigned short* A1b  = (unsigned short*)(ws + O_A1);   // exact overlay of G1b
    float* numv1 = (float*)(ws + O_NUMV1);
    float* s1    = (float*)(ws + O_S1);
    unsigned short* hb = (unsigned short*)(ws + O_H);
    float* Q2   = (float*)(ws + O_Q2);
    float* K2m  = (float*)(ws + O_K2);
    float* V2m  = (float*)(ws + O_V2);
    float* S2m  = (float*)(ws + O_S2M);
    float* G2   = (float*)(ws + O_G2);
    float* A2   = (float*)(ws + O_A2);
    float* numv2 = (float*)(ws + O_NUMV2);
    float* s2   = (float*)(ws + O_S2);
    unsigned short* WB1 = (unsigned short*)(ws + O_WB1);
    unsigned short* WG1 = (unsigned short*)(ws + O_WG1);
    unsigned short* WF1 = (unsigned short*)(ws + O_WF1);
    unsigned short* WB2 = (unsigned short*)(ws + O_WB2);

    hipMemsetAsync(ws + O_DEG, 0, 200000, stream);

    k_detect<<<1, 64, 0, stream>>>((const unsigned int*)ei, flag);
    k_convhist<<<(NE + 255) / 256, 256, 0, stream>>>(ei, flag, srcI, dstI, deg);
    k_scanA<<<196, 256, 0, stream>>>(deg, startA, bsum);
    k_scanB<<<1, 256, 0, stream>>>(bsum);
    k_scanC<<<196, 256, 0, stream>>>(deg, bsum, startA, cursor);
    k_scatter<<<(NE + 255) / 256, 256, 0, stream>>>(srcI, dstI, lu, tE, cursor,
                                                    srcS, orig, relT);
    k_prepw<<<896, 256, 0, stream>>>(Wq1, Wk1, Wv1, Ws1, We1, Wq2, Wk2, Wv2, Ws2,
                                     WB1, WG1, WF1, WB2);
    k_gemm1m<<<dim3(782, 16), 256, 0, stream>>>(
        x, WB1, bq1, bk1, bv1, bs1, Q1b, K1b, V1b, S1mb);
    k_g1m<<<dim3(782, 8), 256, 0, stream>>>(Q1b, WG1, G1b);
    k_agg1<<<4096, 64, 0, stream>>>(startA, srcS, orig, relT, msg, tw, tb,
                                    Q1b, K1b, V1b, G1b, A1b, numv1, s1);
    k_foldC1m<<<dim3(782, 8), 256, 0, stream>>>(A1b, WF1, numv1, s1, S1mb, hb);
    k_gemm2m<<<dim3(782, 2), 256, 0, stream>>>(
        hb, WB2, bq2, bk2, bv2, bs2, Q2, K2m, V2m, S2m);
    k_g2<<<782, 256, 0, stream>>>(Q2, We2, G2);
    k_aggB2<<<4096, 64, 0, stream>>>(startA, srcS, orig, relT, msg, tw, tb,
                                     Q2, K2m, V2m, G2, A2, numv2, s2);
    k_foldC2<<<NN / 8, 256, 0, stream>>>(A2, We2, numv2, s2, S2m, out);
}

// Round 11
// 701.982 us; speedup vs baseline: 1.1478x; 1.1478x over previous
//
#include <hip/hip_runtime.h>
#include <math.h>

#define NN 50000
#define NE 400000
#define RSQRT32 0.17677669529663687f

typedef __attribute__((ext_vector_type(8))) short bf16x8;
typedef __attribute__((ext_vector_type(4))) float f32x4;
#define MFMA_B16(a, b, c) __builtin_amdgcn_mfma_f32_16x16x32_bf16(a, b, c, 0, 0, 0)

// ---------------- workspace layout (bytes) ----------------
#define O_FLAG  0ULL
#define O_BSUM  256ULL                         // 196 ints (scan block sums)
#define O_SRCI  1280ULL                        // E*4
#define O_DSTI  (O_SRCI + 1600000ULL)          // E*4 -> s1 alias after scatter
#define O_DEG   (O_DSTI + 1600000ULL)          // N*4
#define O_CUR   (O_DEG + 200192ULL)            // N*4 -> s2 alias
#define O_START (O_CUR + 200192ULL)            // (N+1)*4
#define O_SRCS  (O_START + 200704ULL)          // E*4
#define O_ORIG  (O_SRCS + 1600000ULL)          // E*4
#define O_RELT  (O_ORIG + 1600000ULL)          // E*4
#define O_Q1    (O_RELT + 1600000ULL)          // N*256*2 bf16; later Q2/K2/V2/S2m fp32
#define O_K1    (O_Q1 + 25600000ULL)           // bf16; later G2 fp32
#define O_V1    (O_K1 + 25600000ULL)           // bf16; later h bf16
#define O_S1M   (O_V1 + 25600000ULL)           // bf16; later A2 fp32
#define O_G1    (O_S1M + 25600000ULL)          // N*1024*2 bf16; A1 aliases exactly; later numv2
#define O_WB1   (O_G1 + 102400000ULL)          // [4][256][128] bf16
#define O_WG1   (O_WB1 + 262144ULL)            // [8][128][32] bf16
#define O_WF1   (O_WG1 + 65536ULL)             // [8][32][128] bf16
#define O_WB2   (O_WF1 + 65536ULL)             // [128][256] bf16
#define O_NUMV1 (O_WB2 + 65536ULL)             // N*256*4 fp32 (dedicated: Q1/K1 live during agg)
#define WS_TOTAL (O_NUMV1 + 51200000ULL)
// aliases
#define O_S1    O_DSTI                         // N*8*4
#define O_A1    O_G1                           // N*1024*2 bf16 (exact overlay of G1)
#define O_H     O_V1                           // N*256*2 bf16
#define O_Q2    O_Q1                           // N*32*4 fp32
#define O_K2    (O_Q1 + 6400000ULL)
#define O_V2    (O_Q1 + 12800000ULL)
#define O_S2M   (O_Q1 + 19200000ULL)
#define O_G2    O_K1                           // N*128*4 fp32
#define O_A2    O_S1M                          // N*128*4 fp32
#define O_NUMV2 O_G1                           // N*32*4 fp32
#define O_S2    O_CUR                          // N*4

__device__ __forceinline__ unsigned short f2bf(float f) {
    unsigned int u = __float_as_uint(f);
    unsigned int r = (u + 0x7fffu + ((u >> 16) & 1u)) >> 16;
    return (unsigned short)r;
}
__device__ __forceinline__ float bf2f(unsigned short u) {
    return __uint_as_float(((unsigned int)u) << 16);
}
__device__ __forceinline__ float4 ld_bf16x4(const unsigned short* p) {
    const ushort4 u = *(const ushort4*)p;
    float4 r;
    r.x = bf2f(u.x); r.y = bf2f(u.y); r.z = bf2f(u.z); r.w = bf2f(u.w);
    return r;
}
__device__ __forceinline__ ushort4 st_bf16x4(float a, float b, float c, float d) {
    ushort4 u; u.x = f2bf(a); u.y = f2bf(b); u.z = f2bf(c); u.w = f2bf(d);
    return u;
}

// ---------------- index dtype detect ----------------
__global__ void k_detect(const unsigned int* ei, int* flag) {
    if (threadIdx.x == 0) {
        int is64 = 1;
        for (int i = 0; i < 64; ++i)
            if (ei[2 * i + 1] != 0u) { is64 = 0; break; }
        *flag = is64;
    }
}

// ---------------- convert + degree histogram (fused) ----------------
__global__ void k_convhist(const void* ei, const int* flag,
                           int* __restrict__ srcI, int* __restrict__ dstI,
                           int* __restrict__ deg) {
    int i = blockIdx.x * 256 + threadIdx.x;
    if (i >= NE) return;
    int s, d;
    if (*flag) {
        const long long* p = (const long long*)ei;
        s = (int)p[i]; d = (int)p[NE + i];
    } else {
        const int* p = (const int*)ei;
        s = p[i]; d = p[NE + i];
    }
    srcI[i] = s;
    dstI[i] = d;
    atomicAdd(&deg[d], 1);
}

// ---------------- parallel 3-phase exclusive scan over deg ----------------
__global__ void k_scanA(const int* __restrict__ deg, int* __restrict__ locs,
                        int* __restrict__ bsum) {
    __shared__ int sm[256];
    const int t = threadIdx.x;
    const int gidx = blockIdx.x * 256 + t;
    int v = (gidx < NN) ? deg[gidx] : 0;
    sm[t] = v;
    __syncthreads();
    for (int off = 1; off < 256; off <<= 1) {
        int u = (t >= off) ? sm[t - off] : 0;
        __syncthreads();
        sm[t] += u;
        __syncthreads();
    }
    if (gidx < NN) locs[gidx] = sm[t];          // inclusive local scan
    if (t == 255) bsum[blockIdx.x] = sm[255];
}

__global__ void k_scanB(int* __restrict__ bsum) {
    __shared__ int sm[256];
    const int t = threadIdx.x;
    int v = (t < 196) ? bsum[t] : 0;
    sm[t] = v;
    __syncthreads();
    for (int off = 1; off < 256; off <<= 1) {
        int u = (t >= off) ? sm[t - off] : 0;
        __syncthreads();
        sm[t] += u;
        __syncthreads();
    }
    if (t < 196) bsum[t] = sm[t] - v;           // exclusive block offsets
}

__global__ void k_scanC(const int* __restrict__ deg, const int* __restrict__ bsum,
                        int* __restrict__ startA, int* __restrict__ cursor) {
    const int t = threadIdx.x;
    const int gidx = blockIdx.x * 256 + t;
    if (gidx < NN) {
        const int ex = startA[gidx] - deg[gidx] + bsum[blockIdx.x];
        startA[gidx] = ex;
        cursor[gidx] = ex;
    }
    if (gidx == 0) startA[NN] = NE;
}

__global__ void k_scatter(const int* __restrict__ srcI, const int* __restrict__ dstI,
                          const float* __restrict__ lu, const float* __restrict__ tE,
                          int* __restrict__ cursor,
                          int* __restrict__ srcS, int* __restrict__ orig,
                          float* __restrict__ relT) {
    int i = blockIdx.x * 256 + threadIdx.x;
    if (i >= NE) return;
    const int d = dstI[i];
    const int s = srcI[i];
    const int pos = atomicAdd(&cursor[d], 1);
    srcS[pos] = s;
    orig[pos] = i;
    relT[pos] = lu[s] - tE[i];
}

// ---------------- weight prep: pack bf16 B^T forms ----------------
__global__ void k_prepw(
    const float* __restrict__ Wq1, const float* __restrict__ Wk1,
    const float* __restrict__ Wv1, const float* __restrict__ Ws1,
    const float* __restrict__ We1,
    const float* __restrict__ Wq2, const float* __restrict__ Wk2,
    const float* __restrict__ Wv2, const float* __restrict__ Ws2,
    unsigned short* __restrict__ WB1, unsigned short* __restrict__ WG1,
    unsigned short* __restrict__ WF1, unsigned short* __restrict__ WB2)
{
    const int i = blockIdx.x * 256 + threadIdx.x;
    if (i < 131072) {                       // WB1[part][n 256][k 128]
        const int part = i >> 15;
        const int rem = i & 32767;
        const int n = rem >> 7, k = rem & 127;
        const float* W = part == 0 ? Wq1 : part == 1 ? Wk1 : part == 2 ? Wv1 : Ws1;
        WB1[i] = f2bf(W[(size_t)k * 256 + n]);
    } else if (i < 163840) {                // WG1[h][ko 128][c 32]
        const int j = i - 131072;
        const int h = j >> 12, ko = (j >> 5) & 127, c = j & 31;
        WG1[j] = f2bf(We1[(size_t)ko * 256 + h * 32 + c]);
    } else if (i < 196608) {                // WF1[h][c 32][ko 128]
        const int j = i - 163840;
        const int h = j >> 12, c = (j >> 7) & 31, ko = j & 127;
        WF1[j] = f2bf(We1[(size_t)ko * 256 + h * 32 + c]);
    } else if (i < 229376) {                // WB2[col 128][k 256]
        const int j = i - 196608;
        const int col = j >> 8, k = j & 255;
        const int part = col >> 5, pc = col & 31;
        const float* W = part == 0 ? Wq2 : part == 1 ? Wk2 : part == 2 ? Wv2 : Ws2;
        WB2[j] = f2bf(W[(size_t)k * 32 + pc]);
    }
}

// ---------------- MFMA node GEMM layer 1 ----------------
__global__ __launch_bounds__(256) void k_gemm1m(
    const float* __restrict__ x, const unsigned short* __restrict__ WB1,
    const float* __restrict__ c0, const float* __restrict__ c1,
    const float* __restrict__ c2, const float* __restrict__ c3,
    unsigned short* __restrict__ Q1b, unsigned short* __restrict__ K1b,
    unsigned short* __restrict__ V1b, unsigned short* __restrict__ S1mb)
{
    __shared__ unsigned short As[64 * 136];
    __shared__ unsigned short Bs[64 * 136];
    const int t = threadIdx.x;
    const int row0 = blockIdx.x * 64;
    const int by = blockIdx.y;
    const int part = by >> 2;
    const int pcol0 = (by & 3) * 64;
    const float* bp = part == 0 ? c0 : part == 1 ? c1 : part == 2 ? c2 : c3;
    unsigned short* Ob = part == 0 ? Q1b : part == 1 ? K1b : part == 2 ? V1b : S1mb;

    {
        const int r = t >> 2, cc = (t & 3) * 32;
        const int gr = row0 + r;
        unsigned short* dst = As + r * 136 + cc;
        if (gr < NN) {
            const float4* xp = (const float4*)(x + (size_t)gr * 128 + cc);
            #pragma unroll
            for (int i = 0; i < 8; ++i) {
                const float4 v = xp[i];
                *(ushort4*)(dst + 4 * i) = st_bf16x4(v.x, v.y, v.z, v.w);
            }
        } else {
            const ushort4 z = {0, 0, 0, 0};
            #pragma unroll
            for (int i = 0; i < 8; ++i) *(ushort4*)(dst + 4 * i) = z;
        }
    }
    {
        const int n = t >> 2, kk = (t & 3) * 32;
        const unsigned short* src = WB1 + ((size_t)part * 256 + pcol0 + n) * 128 + kk;
        unsigned short* dst = Bs + n * 136 + kk;
        #pragma unroll
        for (int i = 0; i < 4; ++i)
            *(bf16x8*)(dst + 8 * i) = *(const bf16x8*)(src + 8 * i);
    }
    __syncthreads();

    const int w = t >> 6, lane = t & 63, m = lane & 15, quad = lane >> 4;
    f32x4 acc[4];
    #pragma unroll
    for (int i = 0; i < 4; ++i) acc[i] = (f32x4){0.f, 0.f, 0.f, 0.f};
    #pragma unroll
    for (int kc = 0; kc < 4; ++kc) {
        const bf16x8 af = *(const bf16x8*)(As + (16 * w + m) * 136 + kc * 32 + quad * 8);
        #pragma unroll
        for (int ct = 0; ct < 4; ++ct) {
            const bf16x8 bf = *(const bf16x8*)(Bs + (16 * ct + m) * 136 + kc * 32 + quad * 8);
            acc[ct] = MFMA_B16(af, bf, acc[ct]);
        }
    }
    #pragma unroll
    for (int ct = 0; ct < 4; ++ct) {
        const int colp = pcol0 + ct * 16 + m;
        const float b = bp[colp];
        #pragma unroll
        for (int r = 0; r < 4; ++r) {
            const int gr = row0 + 16 * w + quad * 4 + r;
            if (gr < NN) Ob[(size_t)gr * 256 + colp] = f2bf(acc[ct][r] + b);
        }
    }
}

// ---------------- MFMA G1 ----------------
__global__ __launch_bounds__(256) void k_g1m(
    const unsigned short* __restrict__ Q1b, const unsigned short* __restrict__ WG1,
    unsigned short* __restrict__ G1b)
{
    __shared__ unsigned short As[64 * 40];
    __shared__ unsigned short Bs[128 * 40];
    const int t = threadIdx.x;
    const int n0 = blockIdx.x * 64;
    const int h = blockIdx.y;
    {
        const int n = t >> 2, c = (t & 3) * 8;
        const int gn = n0 + n;
        bf16x8 v = {};
        if (gn < NN) v = *(const bf16x8*)(Q1b + (size_t)gn * 256 + h * 32 + c);
        *(bf16x8*)(As + n * 40 + c) = v;
    }
    {
        const int ko = t >> 1, c = (t & 1) * 16;
        const unsigned short* src = WG1 + (size_t)h * 4096 + ko * 32 + c;
        *(bf16x8*)(Bs + ko * 40 + c) = *(const bf16x8*)(src);
        *(bf16x8*)(Bs + ko * 40 + c + 8) = *(const bf16x8*)(src + 8);
    }
    __syncthreads();

    const int w = t >> 6, lane = t & 63, m = lane & 15, quad = lane >> 4;
    f32x4 acc[8];
    #pragma unroll
    for (int i = 0; i < 8; ++i) acc[i] = (f32x4){0.f, 0.f, 0.f, 0.f};
    const bf16x8 af = *(const bf16x8*)(As + (16 * w + m) * 40 + quad * 8);
    #pragma unroll
    for (int ct = 0; ct < 8; ++ct) {
        const bf16x8 bf = *(const bf16x8*)(Bs + (16 * ct + m) * 40 + quad * 8);
        acc[ct] = MFMA_B16(af, bf, acc[ct]);
    }
    #pragma unroll
    for (int ct = 0; ct < 8; ++ct) {
        const int k = ct * 16 + m;
        #pragma unroll
        for (int r = 0; r < 4; ++r) {
            const int gn = n0 + 16 * w + quad * 4 + r;
            if (gn < NN) G1b[(size_t)gn * 1024 + h * 128 + k] = f2bf(acc[ct][r]);
        }
    }
}

// ---------------- G2 (fp32) ----------------
__global__ __launch_bounds__(256) void k_g2(
    const float* __restrict__ Q2, const float* __restrict__ We2,
    float* __restrict__ G2)
{
    __shared__ float Qs[64][36];
    __shared__ float Ws[128][36];
    const int t = threadIdx.x;
    const int n0 = blockIdx.x * 64;
    {
        const int n = t >> 2, c8 = (t & 3) * 8;
        float4 v0 = make_float4(0.f,0.f,0.f,0.f), v1 = v0;
        if (n0 + n < NN) {
            v0 = *(const float4*)(Q2 + (size_t)(n0 + n) * 32 + c8);
            v1 = *(const float4*)(Q2 + (size_t)(n0 + n) * 32 + c8 + 4);
        }
        *(float4*)(&Qs[n][c8]) = v0;
        *(float4*)(&Qs[n][c8 + 4]) = v1;
    }
    {
        const int k = t >> 1, c16 = (t & 1) * 16;
        #pragma unroll
        for (int i = 0; i < 4; ++i)
            *(float4*)(&Ws[k][c16 + 4 * i]) =
                *(const float4*)(We2 + (size_t)k * 32 + c16 + 4 * i);
    }
    __syncthreads();
    const int tx = t & 15, ty = t >> 4;
    const int k8 = tx * 8, n4 = ty * 4;
    float acc[4][8] = {};
    #pragma unroll 8
    for (int c = 0; c < 32; ++c) {
        float a[4], b[8];
        #pragma unroll
        for (int i = 0; i < 4; ++i) a[i] = Qs[n4 + i][c];
        #pragma unroll
        for (int j = 0; j < 8; ++j) b[j] = Ws[k8 + j][c];
        #pragma unroll
        for (int i = 0; i < 4; ++i)
            #pragma unroll
            for (int j = 0; j < 8; ++j)
                acc[i][j] += a[i] * b[j];
    }
    #pragma unroll
    for (int i = 0; i < 4; ++i) {
        const int gn = n0 + n4 + i;
        if (gn < NN) {
            float* gp = G2 + (size_t)gn * 128 + k8;
            *(float4*)(gp)     = make_float4(acc[i][0], acc[i][1], acc[i][2], acc[i][3]);
            *(float4*)(gp + 4) = make_float4(acc[i][4], acc[i][5], acc[i][6], acc[i][7]);
        }
    }
}

// ---- k_agg1 macros. Round-11: BRANCH-FREE MEMORY PATH. Evidence (Little's
// law on round-9): wave lifetime ~20us for ~10 edges = ~4800cyc/edge despite
// the 2-deep prefetch -- the guarded issues (`if (j+2<cnt)`) and the divergent
// msg load make outstanding-load counts control-dependent, so the memory
// legalizer merges to conservative s_waitcnt vmcnt(0) at every consume,
// draining the just-issued prefetch (pipeline depth effectively 0). Fix:
// issues ALWAYS execute with a clamped edge index (tail re-reads edge 0 of
// the chunk -- valid, finite data), msg load is unconditional (l&15: all
// lanes read the same 256B row, same cachelines), and the tail body is
// valid-masked via pe = valid ? exp(..) : 0 (accumulators get +0).
#define AGG1_ISSUE(S, JJ)                                                     \
    {                                                                         \
        const int s_ = __shfl(sv, base32 + (JJ));                             \
        rS##S = __shfl(rv, base32 + (JJ));                                    \
        const int o_ = __shfl(ov, base32 + (JJ));                             \
        kS##S = *(const bf16x8*)(kbase + (size_t)s_ * 256);                   \
        vS##S = *(const bf16x8*)(vbase + (size_t)s_ * 256);                   \
        mS##S = *(const float4*)(msg + (size_t)o_ * 64 + (l & 15) * 4);       \
    }

#define AGG1_BODY(KC, VC, MC, RC, VALID)                                      \
    {                                                                         \
        float a0_, a1_, a2_, a3_;                                             \
        if (l < 16) {                                                         \
            a0_ = __cosf((RC) * twl.x + tbl.x);                               \
            a1_ = __cosf((RC) * twl.y + tbl.y);                               \
            a2_ = __cosf((RC) * twl.z + tbl.z);                               \
            a3_ = __cosf((RC) * twl.w + tbl.w);                               \
        } else {                                                              \
            a0_ = (MC).x; a1_ = (MC).y; a2_ = (MC).z; a3_ = (MC).w;           \
        }                                                                     \
        float qk_;                                                            \
        {                                                                     \
            float kf[8];                                                      \
            _Pragma("unroll")                                                 \
            for (int i = 0; i < 8; ++i) kf[i] = bf2f((unsigned short)(KC)[i]); \
            qk_ = q8[0]*kf[0] + q8[1]*kf[1] + q8[2]*kf[2] + q8[3]*kf[3]       \
                + q8[4]*kf[4] + q8[5]*kf[5] + q8[6]*kf[6] + q8[7]*kf[7];      \
        }                                                                     \
        float part[8];                                                        \
        _Pragma("unroll")                                                     \
        for (int h = 0; h < 8; ++h)                                           \
            part[h] = a0_*gv[h][0] + a1_*gv[h][1] + a2_*gv[h][2]              \
                    + a3_*gv[h][3] + (h == hl ? qk_ : 0.f);                   \
        float t4[4];                                                          \
        {                                                                     \
            const bool b_ = (l & 1) != 0;                                     \
            _Pragma("unroll")                                                 \
            for (int i = 0; i < 4; ++i) {                                     \
                const float give = b_ ? part[i] : part[4 + i];                \
                const float keep = b_ ? part[4 + i] : part[i];                \
                t4[i] = keep + __shfl_xor(give, 1);                           \
            }                                                                 \
        }                                                                     \
        float t2[2];                                                          \
        {                                                                     \
            const bool b_ = (l & 2) != 0;                                     \
            _Pragma("unroll")                                                 \
            for (int i = 0; i < 2; ++i) {                                     \
                const float give = b_ ? t4[i] : t4[2 + i];                    \
                const float keep = b_ ? t4[2 + i] : t4[i];                    \
                t2[i] = keep + __shfl_xor(give, 2);                           \
            }                                                                 \
        }                                                                     \
        float t1;                                                             \
        {                                                                     \
            const bool b_ = (l & 4) != 0;                                     \
            const float give = b_ ? t2[0] : t2[1];                            \
            const float keep = b_ ? t2[1] : t2[0];                            \
            t1 = keep + __shfl_xor(give, 4);                                  \
        }                                                                     \
        t1 += __shfl_xor(t1, 8);                                              \
        t1 += __shfl_xor(t1, 16);                                             \
        const float pe = (VALID) ? __expf(fminf(t1 * RSQRT32, 80.f)) : 0.f;   \
        /* lane brev3(h) holds head h; pv for this lane's head via 1 shfl */  \
        float p_all[8];                                                       \
        p_all[0] = __shfl(pe, base32 + 0);                                    \
        p_all[1] = __shfl(pe, base32 + 4);                                    \
        p_all[2] = __shfl(pe, base32 + 2);                                    \
        p_all[3] = __shfl(pe, base32 + 6);                                    \
        p_all[4] = __shfl(pe, base32 + 1);                                    \
        p_all[5] = __shfl(pe, base32 + 5);                                    \
        p_all[6] = __shfl(pe, base32 + 3);                                    \
        p_all[7] = __shfl(pe, base32 + 7);                                    \
        const float pv = __shfl(pe, pvl);                                     \
        _Pragma("unroll")                                                     \
        for (int h = 0; h < 8; ++h) {                                         \
            a1acc[h][0] += p_all[h]*a0_; a1acc[h][1] += p_all[h]*a1_;         \
            a1acc[h][2] += p_all[h]*a2_; a1acc[h][3] += p_all[h]*a3_;         \
        }                                                                     \
        {                                                                     \
            float vf[8];                                                      \
            _Pragma("unroll")                                                 \
            for (int i = 0; i < 8; ++i) vf[i] = bf2f((unsigned short)(VC)[i]); \
            nv[0] += pv*vf[0]; nv[1] += pv*vf[1]; nv[2] += pv*vf[2]; nv[3] += pv*vf[3]; \
            nv[4] += pv*vf[4]; nv[5] += pv*vf[5]; nv[6] += pv*vf[6]; nv[7] += pv*vf[7]; \
            sacc += pv;                                                       \
        }                                                                     \
    }

// ---------------- FUSED layer-1 attention + aggregation (dst-centric) ----------
// block = 1 wave x 2 dsts (64 threads), grid NN/2. Lane-parallel clamped index
// loads + branch-free 2-stage prefetch + halving butterfly.
__global__ __launch_bounds__(64) __attribute__((amdgpu_waves_per_eu(3)))
void k_agg1(
    const int* __restrict__ startA, const int* __restrict__ srcS,
    const int* __restrict__ orig, const float* __restrict__ relT,
    const float* __restrict__ msg, const float* __restrict__ tw,
    const float* __restrict__ tb,
    const unsigned short* __restrict__ Q1b, const unsigned short* __restrict__ K1b,
    const unsigned short* __restrict__ V1b, const unsigned short* G1b,
    unsigned short* A1b, float* __restrict__ numv1, float* __restrict__ s1)
{
    const int t = threadIdx.x;
    const int g = t >> 5, l = t & 31;
    const int base32 = (t & 63) & 32;
    const int d = blockIdx.x * 2 + g;
    const int eb = startA[d], ee = startA[d + 1];
    const int hl = l >> 2;   // head owning this lane's 8-channel q/k/v slice
    // lane holding this head's reduced logit: brev3(hl) within the half-wave
    const int pvl = base32 + (((hl & 1) << 2) | (hl & 2) | (hl >> 2));

    float q8[8];
    {
        const unsigned short* qp = Q1b + (size_t)d * 256 + l * 8;
        const float4 q0 = ld_bf16x4(qp), q1 = ld_bf16x4(qp + 4);
        q8[0]=q0.x; q8[1]=q0.y; q8[2]=q0.z; q8[3]=q0.w;
        q8[4]=q1.x; q8[5]=q1.y; q8[6]=q1.z; q8[7]=q1.w;
    }
    float gv[8][4];
    #pragma unroll
    for (int h = 0; h < 8; ++h) {
        const float4 gg = ld_bf16x4(G1b + (size_t)d * 1024 + h * 128 + l * 4);
        gv[h][0]=gg.x; gv[h][1]=gg.y; gv[h][2]=gg.z; gv[h][3]=gg.w;
    }
    float4 twl = make_float4(0.f,0.f,0.f,0.f), tbl = twl;
    if (l < 16) {
        twl = *(const float4*)(tw + l * 4);
        tbl = *(const float4*)(tb + l * 4);
    }

    float a1acc[8][4] = {};
    float nv[8] = {};
    float sacc = 0.f;

    const unsigned short* kbase = K1b + l * 8;
    const unsigned short* vbase = V1b + l * 8;

    for (int c = eb; c < ee; c += 32) {
        const int cnt = (ee - c < 32) ? (ee - c) : 32;
        const int idx = (c + l < ee) ? (c + l) : (ee - 1);   // clamped, always valid
        const int   sv = srcS[idx];                          // lane-parallel, coalesced
        const float rv = relT[idx];
        const int   ov = orig[idx];

        bf16x8 kS0 = {}, vS0 = {}, kS1 = {}, vS1 = {};
        float4 mS0 = make_float4(0.f,0.f,0.f,0.f), mS1 = mS0;
        float  rS0 = 0.f, rS1 = 0.f;

        AGG1_ISSUE(0, 0);
        AGG1_ISSUE(1, (cnt > 1) ? 1 : 0);
        for (int j = 0; j < cnt; j += 2) {
            {
                const bf16x8 kc_ = kS0, vc_ = vS0;
                const float4 mc_ = mS0;
                const float  rc_ = rS0;
                AGG1_ISSUE(0, (j + 2 < cnt) ? (j + 2) : 0);
                AGG1_BODY(kc_, vc_, mc_, rc_, 1)
            }
            {
                const bf16x8 kc_ = kS1, vc_ = vS1;
                const float4 mc_ = mS1;
                const float  rc_ = rS1;
                AGG1_ISSUE(1, (j + 3 < cnt) ? (j + 3) : 0);
                AGG1_BODY(kc_, vc_, mc_, rc_, (j + 1 < cnt))
            }
        }
    }

    #pragma unroll
    for (int h = 0; h < 8; ++h)
        *(ushort4*)(A1b + (size_t)d * 1024 + h * 128 + l * 4) =
            st_bf16x4(a1acc[h][0], a1acc[h][1], a1acc[h][2], a1acc[h][3]);
    float* np = numv1 + (size_t)d * 256 + l * 8;
    *(float4*)(np)     = make_float4(nv[0], nv[1], nv[2], nv[3]);
    *(float4*)(np + 4) = make_float4(nv[4], nv[5], nv[6], nv[7]);
    if ((l & 3) == 0) s1[(size_t)d * 8 + hl] = sacc;
}

// ---------------- MFMA fold layer 1 ----------------
__global__ __launch_bounds__(256) void k_foldC1m(
    const unsigned short* __restrict__ A1b, const unsigned short* __restrict__ WF1,
    const float* __restrict__ numv1, const float* __restrict__ s1,
    const unsigned short* __restrict__ S1mb, unsigned short* __restrict__ hb)
{
    __shared__ unsigned short As[64 * 136];
    __shared__ unsigned short Bs[32 * 136];
    const int t = threadIdx.x;
    const int n0 = blockIdx.x * 64;
    const int h = blockIdx.y;
    {
        const int n = t >> 2, kk = (t & 3) * 32;
        const int gn = n0 + n;
        unsigned short* dst = As + n * 136 + kk;
        if (gn < NN) {
            const unsigned short* src = A1b + (size_t)gn * 1024 + h * 128 + kk;
            #pragma unroll
            for (int i = 0; i < 4; ++i)
                *(bf16x8*)(dst + 8 * i) = *(const bf16x8*)(src + 8 * i);
        } else {
            const bf16x8 z = {};
            #pragma unroll
            for (int i = 0; i < 4; ++i) *(bf16x8*)(dst + 8 * i) = z;
        }
    }
    {
        const int c = t >> 3, kk = (t & 7) * 16;
        const unsigned short* src = WF1 + (size_t)h * 4096 + c * 128 + kk;
        *(bf16x8*)(Bs + c * 136 + kk) = *(const bf16x8*)(src);
        *(bf16x8*)(Bs + c * 136 + kk + 8) = *(const bf16x8*)(src + 8);
    }
    __syncthreads();

    const int w = t >> 6, lane = t & 63, m = lane & 15, quad = lane >> 4;
    f32x4 acc[2];
    acc[0] = (f32x4){0.f, 0.f, 0.f, 0.f};
    acc[1] = (f32x4){0.f, 0.f, 0.f, 0.f};
    #pragma unroll
    for (int kc = 0; kc < 4; ++kc) {
        const bf16x8 af = *(const bf16x8*)(As + (16 * w + m) * 136 + kc * 32 + quad * 8);
        #pragma unroll
        for (int ct = 0; ct < 2; ++ct) {
            const bf16x8 bf = *(const bf16x8*)(Bs + (16 * ct + m) * 136 + kc * 32 + quad * 8);
            acc[ct] = MFMA_B16(af, bf, acc[ct]);
        }
    }
    #pragma unroll
    for (int ct = 0; ct < 2; ++ct) {
        const int c = ct * 16 + m;
        #pragma unroll
        for (int r = 0; r < 4; ++r) {
            const int gn = n0 + 16 * w + quad * 4 + r;
            if (gn < NN) {
                const float s = s1[(size_t)gn * 8 + h] + 1e-16f;
                const float nvv = numv1[(size_t)gn * 256 + h * 32 + c];
                const float sk = bf2f(S1mb[(size_t)gn * 256 + h * 32 + c]);
                float v = (acc[ct][r] + nvv) / s + sk;
                v = v > 0.f ? v : 0.f;
                hb[(size_t)gn * 256 + h * 32 + c] = f2bf(v);
            }
        }
    }
}

// ---------------- MFMA node GEMM layer 2 ----------------
__global__ __launch_bounds__(256) void k_gemm2m(
    const unsigned short* __restrict__ hb, const unsigned short* __restrict__ WB2,
    const float* __restrict__ c0, const float* __restrict__ c1,
    const float* __restrict__ c2, const float* __restrict__ c3,
    float* __restrict__ O0, float* __restrict__ O1,
    float* __restrict__ O2, float* __restrict__ O3)
{
    __shared__ unsigned short As[64 * 136];
    __shared__ unsigned short Bs[64 * 136];
    const int t = threadIdx.x;
    const int row0 = blockIdx.x * 64;
    const int coly = blockIdx.y;
    const int w = t >> 6, lane = t & 63, m = lane & 15, quad = lane >> 4;

    f32x4 acc[4];
    #pragma unroll
    for (int i = 0; i < 4; ++i) acc[i] = (f32x4){0.f, 0.f, 0.f, 0.f};

    for (int kb = 0; kb < 2; ++kb) {
        if (kb) __syncthreads();
        {
            const int r = t >> 2, kk = (t & 3) * 32;
            const int gr = row0 + r;
            unsigned short* dst = As + r * 136 + kk;
            if (gr < NN) {
                const unsigned short* src = hb + (size_t)gr * 256 + kb * 128 + kk;
                #pragma unroll
                for (int i = 0; i < 4; ++i)
                    *(bf16x8*)(dst + 8 * i) = *(const bf16x8*)(src + 8 * i);
            } else {
                const bf16x8 z = {};
                #pragma unroll
                for (int i = 0; i < 4; ++i) *(bf16x8*)(dst + 8 * i) = z;
            }
        }
        {
            const int n = t >> 2, kk = (t & 3) * 32;
            const unsigned short* src = WB2 + (size_t)(coly * 64 + n) * 256 + kb * 128 + kk;
            unsigned short* dst = Bs + n * 136 + kk;
            #pragma unroll
            for (int i = 0; i < 4; ++i)
                *(bf16x8*)(dst + 8 * i) = *(const bf16x8*)(src + 8 * i);
        }
        __syncthreads();
        #pragma unroll
        for (int kc = 0; kc < 4; ++kc) {
            const bf16x8 af = *(const bf16x8*)(As + (16 * w + m) * 136 + kc * 32 + quad * 8);
            #pragma unroll
            for (int ct = 0; ct < 4; ++ct) {
                const bf16x8 bf = *(const bf16x8*)(Bs + (16 * ct + m) * 136 + kc * 32 + quad * 8);
                acc[ct] = MFMA_B16(af, bf, acc[ct]);
            }
        }
    }
    #pragma unroll
    for (int ct = 0; ct < 4; ++ct) {
        const int col = coly * 64 + ct * 16 + m;
        const int part = col >> 5, pc = col & 31;
        const float* bb = part == 0 ? c0 : part == 1 ? c1 : part == 2 ? c2 : c3;
        float* Op = part == 0 ? O0 : part == 1 ? O1 : part == 2 ? O2 : O3;
        const float b = bb[pc];
        #pragma unroll
        for (int r = 0; r < 4; ++r) {
            const int gr = row0 + 16 * w + quad * 4 + r;
            if (gr < NN) Op[(size_t)gr * 32 + pc] = acc[ct][r] + b;
        }
    }
}

// ---- k_aggB2 macros (branch-free memory path, depth 2) ----
#define AGG2_ISSUE(S, JJ)                                                     \
    {                                                                         \
        const int s_ = __shfl(sv, base32 + (JJ));                             \
        rS##S = __shfl(rv, base32 + (JJ));                                    \
        const int o_ = __shfl(ov, base32 + (JJ));                             \
        kS##S = K2[(size_t)s_ * 32 + l];                                      \
        vS##S = V2[(size_t)s_ * 32 + l];                                      \
        mS##S = *(const float4*)(msg + (size_t)o_ * 64 + (l & 15) * 4);       \
    }

#define AGG2_BODY(KC, VC, MC, RC, VALID)                                      \
    {                                                                         \
        float a0_, a1_, a2_, a3_;                                             \
        if (l < 16) {                                                         \
            a0_ = __cosf((RC) * twl.x + tbl.x);                               \
            a1_ = __cosf((RC) * twl.y + tbl.y);                               \
            a2_ = __cosf((RC) * twl.z + tbl.z);                               \
            a3_ = __cosf((RC) * twl.w + tbl.w);                               \
        } else {                                                              \
            a0_ = (MC).x; a1_ = (MC).y; a2_ = (MC).z; a3_ = (MC).w;           \
        }                                                                     \
        float part = q2l * (KC);                                              \
        part += a0_ * g2l.x + a1_ * g2l.y + a2_ * g2l.z + a3_ * g2l.w;        \
        part += __shfl_xor(part, 1);                                          \
        part += __shfl_xor(part, 2);                                          \
        part += __shfl_xor(part, 4);                                          \
        part += __shfl_xor(part, 8);                                          \
        part += __shfl_xor(part, 16);                                         \
        const float p = (VALID) ? __expf(fminf(part * RSQRT32, 80.f)) : 0.f;  \
        acc2[0] += p * a0_; acc2[1] += p * a1_;                               \
        acc2[2] += p * a2_; acc2[3] += p * a3_;                               \
        nvacc += p * (VC);                                                    \
        sacc += p;                                                            \
    }

// ---------------- layer 2 fused p + aggregate (branch-free pipeline) --------
// block = 1 wave x 2 dsts (64 threads), grid NN/2.
__global__ __launch_bounds__(64) __attribute__((amdgpu_waves_per_eu(4)))
void k_aggB2(
    const int* __restrict__ startA, const int* __restrict__ srcS,
    const int* __restrict__ orig, const float* __restrict__ relT,
    const float* __restrict__ msg, const float* __restrict__ tw,
    const float* __restrict__ tb,
    const float* __restrict__ Q2, const float* __restrict__ K2,
    const float* __restrict__ V2, const float* __restrict__ G2,
    float* __restrict__ A2, float* __restrict__ numv2, float* __restrict__ s2)
{
    const int t = threadIdx.x;
    const int g = t >> 5, l = t & 31;
    const int base32 = (t & 63) & 32;
    const int d = blockIdx.x * 2 + g;
    const int eb = startA[d], ee = startA[d + 1];

    const float q2l = Q2[(size_t)d * 32 + l];
    const float4 g2l = *(const float4*)(G2 + (size_t)d * 128 + l * 4);
    float4 twl = make_float4(0.f,0.f,0.f,0.f), tbl = twl;
    if (l < 16) {
        twl = *(const float4*)(tw + l * 4);
        tbl = *(const float4*)(tb + l * 4);
    }
    float acc2[4] = {};
    float nvacc = 0.f, sacc = 0.f;

    for (int c = eb; c < ee; c += 32) {
        const int cnt = (ee - c < 32) ? (ee - c) : 32;
        const int idx = (c + l < ee) ? (c + l) : (ee - 1);   // clamped, always valid
        const int   sv = srcS[idx];
        const float rv = relT[idx];
        const int   ov = orig[idx];

        float kS0 = 0.f, vS0 = 0.f, kS1 = 0.f, vS1 = 0.f;
        float rS0 = 0.f, rS1 = 0.f;
        float4 mS0 = make_float4(0.f,0.f,0.f,0.f), mS1 = mS0;

        AGG2_ISSUE(0, 0);
        AGG2_ISSUE(1, (cnt > 1) ? 1 : 0);
        for (int j = 0; j < cnt; j += 2) {
            {
                const float kc_ = kS0, vc_ = vS0;
                const float4 mc_ = mS0;
                const float  rc_ = rS0;
                AGG2_ISSUE(0, (j + 2 < cnt) ? (j + 2) : 0);
                AGG2_BODY(kc_, vc_, mc_, rc_, 1)
            }
            {
                const float kc_ = kS1, vc_ = vS1;
                const float4 mc_ = mS1;
                const float  rc_ = rS1;
                AGG2_ISSUE(1, (j + 3 < cnt) ? (j + 3) : 0);
                AGG2_BODY(kc_, vc_, mc_, rc_, (j + 1 < cnt))
            }
        }
    }

    *(float4*)(A2 + (size_t)d * 128 + l * 4) =
        make_float4(acc2[0], acc2[1], acc2[2], acc2[3]);
    numv2[(size_t)d * 32 + l] = nvacc;
    if (l == 0) s2[d] = sacc;
}

// ---------------- fold layer 2 ----------------
__global__ __launch_bounds__(256) void k_foldC2(
    const float* __restrict__ A2, const float* __restrict__ We2,
    const float* __restrict__ numv2, const float* __restrict__ s2,
    const float* __restrict__ S2m, float* __restrict__ out)
{
    __shared__ float Ws[128][36];
    const int t = threadIdx.x;
    {
        const int k = t >> 1, c16 = (t & 1) * 16;
        #pragma unroll
        for (int i = 0; i < 4; ++i)
            *(float4*)(&Ws[k][c16 + 4 * i]) =
                *(const float4*)(We2 + (size_t)k * 32 + c16 + 4 * i);
    }
    __syncthreads();
    const int n = blockIdx.x * 8 + (t >> 5);
    const int c = t & 31;
    const float* ap = A2 + (size_t)n * 128;
    float acc = 0.f;
    #pragma unroll 8
    for (int k = 0; k < 128; k += 4) {
        const float4 a4 = *(const float4*)(ap + k);
        acc += a4.x * Ws[k][c] + a4.y * Ws[k + 1][c] +
               a4.z * Ws[k + 2][c] + a4.w * Ws[k + 3][c];
    }
    const float s = s2[n] + 1e-16f;
    float v = (numv2[(size_t)n * 32 + c] + acc) / s + S2m[(size_t)n * 32 + c];
    out[(size_t)n * 32 + c] = v > 0.f ? v : 0.f;
}

extern "C" void kernel_launch(void* const* d_in, const int* in_sizes, int n_in,
                              void* d_out, int out_size, void* d_ws, size_t ws_size,
                              hipStream_t stream) {
    const float* x   = (const float*)d_in[0];
    const float* lu  = (const float*)d_in[1];
    const void*  ei  = d_in[2];
    const float* tE  = (const float*)d_in[3];
    const float* msg = (const float*)d_in[4];
    const float* tw  = (const float*)d_in[5];
    const float* tb  = (const float*)d_in[6];
    const float* Wq1 = (const float*)d_in[7];  const float* bq1 = (const float*)d_in[8];
    const float* Wk1 = (const float*)d_in[9];  const float* bk1 = (const float*)d_in[10];
    const float* Wv1 = (const float*)d_in[11]; const float* bv1 = (const float*)d_in[12];
    const float* We1 = (const float*)d_in[13];
    const float* Ws1 = (const float*)d_in[14]; const float* bs1 = (const float*)d_in[15];
    const float* Wq2 = (const float*)d_in[16]; const float* bq2 = (const float*)d_in[17];
    const float* Wk2 = (const float*)d_in[18]; const float* bk2 = (const float*)d_in[19];
    const float* Wv2 = (const float*)d_in[20]; const float* bv2 = (const float*)d_in[21];
    const float* We2 = (const float*)d_in[22];
    const float* Ws2 = (const float*)d_in[23]; const float* bs2 = (const float*)d_in[24];
    float* out = (float*)d_out;
    char* ws = (char*)d_ws;

    if (ws_size < WS_TOTAL) return;

    int* flag   = (int*)(ws + O_FLAG);
    int* bsum   = (int*)(ws + O_BSUM);
    int* srcI   = (int*)(ws + O_SRCI);
    int* dstI   = (int*)(ws + O_DSTI);
    int* deg    = (int*)(ws + O_DEG);
    int* cursor = (int*)(ws + O_CUR);
    int* startA = (int*)(ws + O_START);
    int* srcS   = (int*)(ws + O_SRCS);
    int* orig   = (int*)(ws + O_ORIG);
    float* relT = (float*)(ws + O_RELT);
    unsigned short* Q1b  = (unsigned short*)(ws + O_Q1);
    unsigned short* K1b  = (unsigned short*)(ws + O_K1);
    unsigned short* V1b  = (unsigned short*)(ws + O_V1);
    unsigned short* S1mb = (unsigned short*)(ws + O_S1M);
    unsigned short* G1b  = (unsigned short*)(ws + O_G1);
    unsigned short* A1b  = (unsigned short*)(ws + O_A1);   // exact overlay of G1b
    float* numv1 = (float*)(ws + O_NUMV1);
    float* s1    = (float*)(ws + O_S1);
    unsigned short* hb = (unsigned short*)(ws + O_H);
    float* Q2   = (float*)(ws + O_Q2);
    float* K2m  = (float*)(ws + O_K2);
    float* V2m  = (float*)(ws + O_V2);
    float* S2m  = (float*)(ws + O_S2M);
    float* G2   = (float*)(ws + O_G2);
    float* A2   = (float*)(ws + O_A2);
    float* numv2 = (float*)(ws + O_NUMV2);
    float* s2   = (float*)(ws + O_S2);
    unsigned short* WB1 = (unsigned short*)(ws + O_WB1);
    unsigned short* WG1 = (unsigned short*)(ws + O_WG1);
    unsigned short* WF1 = (unsigned short*)(ws + O_WF1);
    unsigned short* WB2 = (unsigned short*)(ws + O_WB2);

    hipMemsetAsync(ws + O_DEG, 0, 200000, stream);

    k_detect<<<1, 64, 0, stream>>>((const unsigned int*)ei, flag);
    k_convhist<<<(NE + 255) / 256, 256, 0, stream>>>(ei, flag, srcI, dstI, deg);
    k_scanA<<<196, 256, 0, stream>>>(deg, startA, bsum);
    k_scanB<<<1, 256, 0, stream>>>(bsum);
    k_scanC<<<196, 256, 0, stream>>>(deg, bsum, startA, cursor);
    k_scatter<<<(NE + 255) / 256, 256, 0, stream>>>(srcI, dstI, lu, tE, cursor,
                                                    srcS, orig, relT);
    k_prepw<<<896, 256, 0, stream>>>(Wq1, Wk1, Wv1, Ws1, We1, Wq2, Wk2, Wv2, Ws2,
                                     WB1, WG1, WF1, WB2);
    k_gemm1m<<<dim3(782, 16), 256, 0, stream>>>(
        x, WB1, bq1, bk1, bv1, bs1, Q1b, K1b, V1b, S1mb);
    k_g1m<<<dim3(782, 8), 256, 0, stream>>>(Q1b, WG1, G1b);
    k_agg1<<<NN / 2, 64, 0, stream>>>(startA, srcS, orig, relT, msg, tw, tb,
                                      Q1b, K1b, V1b, G1b, A1b, numv1, s1);
    k_foldC1m<<<dim3(782, 8), 256, 0, stream>>>(A1b, WF1, numv1, s1, S1mb, hb);
    k_gemm2m<<<dim3(782, 2), 256, 0, stream>>>(
        hb, WB2, bq2, bk2, bv2, bs2, Q2, K2m, V2m, S2m);
    k_g2<<<782, 256, 0, stream>>>(Q2, We2, G2);
    k_aggB2<<<NN / 2, 64, 0, stream>>>(startA, srcS, orig, relT, msg, tw, tb,
                                       Q2, K2m, V2m, G2, A2, numv2, s2);
    k_foldC2<<<NN / 8, 256, 0, stream>>>(A2, We2, numv2, s2, S2m, out);
}